// Round 13
// baseline (4392.562 us; speedup 1.0000x reference)
//
#include <hip/hip_runtime.h>

typedef unsigned short u16;
typedef __attribute__((ext_vector_type(4))) float f32x4;
typedef __attribute__((ext_vector_type(2))) float f32x2;
typedef __attribute__((ext_vector_type(8))) short short8;

#define B_ 32
#define P_ 196
#define T_ 64
#define V_ 32000
#define SLABF 17408   // 68 KB slab stride in floats
#define GO_B  8192    // go-copy lines base (ints)
#define GRP_B 8448    // group-flag base (ints)

// Cross-block exchange (proven r4-r12): producers = relaxed agent-scope atomic
// stores (write-through to MALL); consumers = plain cached loads on t-indexed
// slabs (fresh addresses per step; across graph replays values are identical).
#define AT_LOAD(p)     __hip_atomic_load((p), __ATOMIC_RELAXED, __HIP_MEMORY_SCOPE_AGENT)
#define AT_STORE(p,v)  __hip_atomic_store((p), (v), __ATOMIC_RELAXED, __HIP_MEMORY_SCOPE_AGENT)

__device__ __forceinline__ u16 f2bf(float x){
  unsigned int u = __float_as_uint(x);
  u += 0x7FFFu + ((u >> 16) & 1u);
  return (u16)(u >> 16);
}
__device__ __forceinline__ float bf2f(u16 x){
  return __uint_as_float(((unsigned int)x) << 16);
}
__device__ __forceinline__ float sigf(float x){ return 1.0f/(1.0f + __expf(-x)); }
__device__ __forceinline__ float tanhfast(float x){
  float e = __expf(-2.0f*fabsf(x));
  float t = (1.0f - e)/(1.0f + e);
  return x >= 0.0f ? t : -t;
}

// ---------- setup kernels ----------

__global__ __launch_bounds__(256) void k_cvt_bf16(const float* __restrict__ s,
                                                  u16* __restrict__ d, int n8){
  int i = blockIdx.x*256 + threadIdx.x;
  if (i >= n8) return;
  const f32x4* sp = (const f32x4*)(s + (size_t)i*8);
  f32x4 a = sp[0], b = sp[1];
  short8 v;
#pragma unroll
  for (int j=0;j<4;++j){ v[j] = (short)f2bf(a[j]); v[4+j] = (short)f2bf(b[j]); }
  *(short8*)(d + (size_t)i*8) = v;
}

__global__ __launch_bounds__(256) void k_wencT(const float* __restrict__ W, u16* __restrict__ WT){
  int tid = threadIdx.x;
  int kc = tid & 63, a = blockIdx.x*4 + (tid >> 6);
  short8 v;
#pragma unroll
  for (int j=0;j<8;++j) v[j] = (short)f2bf(W[(kc*8+j)*512 + a]);
  *(short8*)(WT + a*512 + kc*8) = v;
}

__global__ __launch_bounds__(256) void k_mean(const float* __restrict__ enc, float* __restrict__ mean){
  int b = blockIdx.x, tid = threadIdx.x;
  f32x2 acc; acc.x = 0.f; acc.y = 0.f;
  for (int p=0;p<P_;++p){
    f32x2 v = *(const f32x2*)(enc + ((size_t)(b*P_+p))*512 + tid*2);
    acc.x += v.x; acc.y += v.y;
  }
  acc.x *= (1.0f/196.0f); acc.y *= (1.0f/196.0f);
  *(f32x2*)(mean + b*512 + tid*2) = acc;
}

__global__ __launch_bounds__(256) void k_init_state(const float* __restrict__ mean,
    const float* __restrict__ Wh, const float* __restrict__ bh,
    const float* __restrict__ Wc, const float* __restrict__ bc,
    float* __restrict__ h0, float* __restrict__ h1,
    float* __restrict__ c0, float* __restrict__ c1){
  int bid = blockIdx.x;
  int which = bid >> 7, r = (bid >> 2) & 31, jg = bid & 3;
  const float* W = which ? Wc : Wh;
  const float* bb = which ? bc : bh;
  __shared__ float m[512];
  for (int i=threadIdx.x; i<512; i+=256) m[i] = mean[r*512 + i];
  __syncthreads();
  int j = jg*256 + threadIdx.x;
  float acc = bb[j];
  for (int e=0;e<512;++e) acc += m[e]*W[e*1024 + j];
  int l = r >> 4;
  int bb2 = ((r & 15) << 1) | (j >> 9);
  int hh = j & 511;
  float* dst = which ? (l ? c1 : c0) : (l ? h1 : h0);
  dst[bb2*512 + hh] = acc;
}

// fused LSTM weights: W0f[2048][1536] = [Wih0 | Whh0], W1f[2048][1024] = [Wih1 | Whh1]
__global__ __launch_bounds__(256) void k_fuse_w(const float* __restrict__ Wih0,
    const float* __restrict__ Whh0, const float* __restrict__ Wih1,
    const float* __restrict__ Whh1, float* __restrict__ W0f, float* __restrict__ W1f){
  int r = blockIdx.x, tid = threadIdx.x;
  if (r < 2048){
    for (int k=tid; k<1536; k+=256)
      W0f[(size_t)r*1536+k] = (k<1024) ? Wih0[(size_t)r*1024+k] : Whh0[(size_t)r*512 + (k-1024)];
  } else {
    int r1 = r - 2048;
    for (int k=tid; k<1024; k+=256)
      W1f[(size_t)r1*1024+k] = (k<512) ? Wih1[(size_t)r1*512+k] : Whh1[(size_t)r1*512 + (k-512)];
  }
}

// ---------- bf16 GEMM (LDS pad 40 u16): C[M][N] = A[M][512]*Bm[N][512]^T + bias ----------
#define LDAP 40
__global__ __launch_bounds__(256) void k_gemm_bf16(
    const u16* __restrict__ A, const u16* __restrict__ Bm,
    const float* __restrict__ bias, float* __restrict__ C, int N){
  __shared__ __align__(16) u16 As[128*LDAP];
  __shared__ __align__(16) u16 Bs[128*LDAP];
  int tid = threadIdx.x, l = tid & 63, w = tid >> 6;
  int m0 = blockIdx.x * 128, n0 = blockIdx.y * 128;
  int wm = w >> 1, wn = w & 1;
  f32x4 acc[4][4];
#pragma unroll
  for (int a=0;a<4;++a)
#pragma unroll
    for (int b=0;b<4;++b) acc[a][b] = (f32x4)0.0f;
  int srow = tid >> 2, schunk = tid & 3;
  const u16* gA = A + (size_t)(m0 + srow)*512 + schunk*8;
  const u16* gB = Bm + (size_t)(n0 + srow)*512 + schunk*8;
  int lr = l & 15, lk = (l >> 4) * 8;
  for (int k0 = 0; k0 < 512; k0 += 32){
    short8 va0 = *(const short8*)(gA + k0);
    short8 va1 = *(const short8*)(gA + (size_t)64*512 + k0);
    short8 vb0 = *(const short8*)(gB + k0);
    short8 vb1 = *(const short8*)(gB + (size_t)64*512 + k0);
    __syncthreads();
    *(short8*)(As + srow*LDAP + schunk*8) = va0;
    *(short8*)(As + (64+srow)*LDAP + schunk*8) = va1;
    *(short8*)(Bs + srow*LDAP + schunk*8) = vb0;
    *(short8*)(Bs + (64+srow)*LDAP + schunk*8) = vb1;
    __syncthreads();
    short8 af[4], bfv[4];
#pragma unroll
    for (int mt=0; mt<4; ++mt) af[mt]  = *(const short8*)(As + (wm*64 + mt*16 + lr)*LDAP + lk);
#pragma unroll
    for (int nt=0; nt<4; ++nt) bfv[nt] = *(const short8*)(Bs + (wn*64 + nt*16 + lr)*LDAP + lk);
#pragma unroll
    for (int mt=0; mt<4; ++mt)
#pragma unroll
      for (int nt=0; nt<4; ++nt)
        acc[mt][nt] = __builtin_amdgcn_mfma_f32_16x16x32_bf16(af[mt], bfv[nt], acc[mt][nt], 0, 0, 0);
  }
#pragma unroll
  for (int mt=0; mt<4; ++mt){
    int row = m0 + wm*64 + mt*16 + ((l >> 4) << 2);
#pragma unroll
    for (int nt=0; nt<4; ++nt){
      int col = n0 + wn*64 + nt*16 + (l & 15);
      float bv = bias[col];
#pragma unroll
      for (int j=0;j<4;++j)
        C[(size_t)(row + j)*N + col] = acc[mt][nt][j] + bv;
    }
  }
}

// ---------- persistent recurrence kernel ----------

struct RA {
  const float* enc; const int* caps; const float* embW;
  const u16* WdecBF; const float* bdec; const float* Wfull; const float* bfull;
  const u16* encattBF; const float* W0f; const float* W1f;
  const float* bih0; const float* bhh0; const float* bih1; const float* bhh1;
  float* h0g; float* h1g; float* att2g; float* ctxg;
  const float* c0init; const float* c1init;
  u16* h1_all; int* sync;
};

// Flat global barrier, split arrive/wait; go fan-out to 8 padded copies
// (each polled by ~32 blocks) written directly by block0 (no relay hop).
__device__ __forceinline__ void g_arrive(int* sync, int gen){
  __syncthreads();   // drain this block's data stores before the flag store
  if (blockIdx.x != 0 && threadIdx.x == 0)
    AT_STORE(&sync[blockIdx.x*32], gen);
}
__device__ __forceinline__ void g_wait(int* sync, int gen){
  int tid = threadIdx.x;
  if (blockIdx.x == 0){
    if (tid >= 1 && tid < 256){
      while (AT_LOAD(&sync[tid*32]) < gen) __builtin_amdgcn_s_sleep(1);
    }
    __syncthreads();
    if (tid < 8) AT_STORE(&sync[GO_B + tid*32], gen);
  } else {
    if (tid == 0){
      while (AT_LOAD(&sync[GO_B + (blockIdx.x & 7)*32]) < gen) __builtin_amdgcn_s_sleep(1);
    }
    __syncthreads();
  }
  asm volatile("" ::: "memory");
}

// LSTM weights LDS-resident, swizzled (r8): float k = ks*32+q*4+e of (row,ch)
// at [row][ch*512 + q*64 + ks*4 + e]. ds_read_b128 -> 16 distinct addresses,
// 2 per bank-quad (free), 4-lane broadcast.
__global__ __launch_bounds__(512) void k_recur(RA a){
  int bid = blockIdx.x, tid = threadIdx.x;
  int lane = tid & 63, wv = tid >> 6;
  __shared__ __align__(16) float w0s[12288];  // 48 KB: 8 rows x 1536
  __shared__ __align__(16) float w1s[8192];   // 32 KB: 8 rows x 1024
  __shared__ float red[1280];                 // P1: h1s|gp ; P23: att2s|gp3|alph
  __shared__ float pa0[264], pa1[264];        // parked partials [r*33 + bb]
  __shared__ float c0s[64], c1s[64];          // [ci*32 + b]
  __shared__ float SinvS;

  int xcd = bid & 7;
  int ab = xcd*4 + ((bid >> 3) & 3);    // attention batch
  int as = bid >> 5, c0col = as*64;     // attention col-slice
  int grp = bid & 31;                   // att2 group id (8 members, as=0..7)
  int bb = tid >> 4, ksg = tid & 15;    // LSTM: batch 0..31, k-slice 0..15

  // one-time: weight rows -> LDS swizzled. local row r = g*2+ci.
  for (int idx = tid; idx < 12288; idx += 512){
    int r = idx / 1536, rem = idx - r*1536;
    int ch = rem >> 9, rem2 = rem & 511;
    int q = rem2 >> 6, rem3 = rem2 & 63;
    int ks = rem3 >> 2, e = rem3 & 3;
    int grow = (r >> 1)*512 + bid*2 + (r & 1);
    w0s[idx] = a.W0f[(size_t)grow*1536 + ch*512 + ks*32 + q*4 + e];
  }
  for (int idx = tid; idx < 8192; idx += 512){
    int r = idx >> 10, rem = idx & 1023;
    int ch = rem >> 9, rem2 = rem & 511;
    int q = rem2 >> 6, rem3 = rem2 & 63;
    int ks = rem3 >> 2, e = rem3 & 3;
    int grow = (r >> 1)*512 + bid*2 + (r & 1);
    w1s[idx] = a.W1f[(size_t)grow*1024 + ch*512 + ks*32 + q*4 + e];
  }
  if (tid < 64){
    int ci = tid >> 5, b = tid & 31, cell = bid*2 + ci;
    c0s[ci*32+b] = a.c0init[b*512 + cell];
    c1s[ci*32+b] = a.c1init[b*512 + cell];
  }
  __syncthreads();

  // prologue: emb-channel partial for t=0 -> pa0
  {
    float a0[8];
#pragma unroll
    for (int r=0;r<8;++r) a0[r] = 0.f;
    int cap = a.caps[bb*T_ + 0];
    const float* ep_ = a.embW + (size_t)cap*512 + ksg*32;
    f32x4 x[8];
#pragma unroll
    for (int q=0;q<8;++q) x[q] = *(const f32x4*)(ep_ + q*4);
    const float* wb = w0s + ksg*4;
#pragma unroll
    for (int q=0;q<8;++q){
      f32x4 xq = x[q];
#pragma unroll
      for (int r=0;r<8;++r){
        f32x4 w4 = *(const f32x4*)(wb + r*1536 + q*64);
        a0[r] = fmaf(xq.x,w4.x, fmaf(xq.y,w4.y, fmaf(xq.z,w4.z, fmaf(xq.w,w4.w, a0[r]))));
      }
    }
#pragma unroll
    for (int r=0;r<8;++r){
      float v = a0[r];
      v += __shfl_xor(v,1); v += __shfl_xor(v,2); v += __shfl_xor(v,4); v += __shfl_xor(v,8);
      if (ksg == 0) pa0[r*33+bb] = v;
    }
  }

  for (int t = 0; t < T_; ++t){
    const float* h1_rd = a.h1g + (size_t)t*SLABF;        // h1(t-1); slot0 = init
    const float* h0_rd = a.h0g + (size_t)t*SLABF;
    float*       h0_wr = a.h0g + (size_t)(t+1)*SLABF;
    float*       h1_wr = a.h1g + (size_t)(t+1)*SLABF;
    float*       at_wr = a.att2g + (size_t)t*SLABF;
    const float* at_rd = at_wr;
    float*       cx_wr = a.ctxg + (size_t)t*SLABF;
    const float* cx_rd = cx_wr;
    int geng = t*3;

    // ---- P1: att2 cols [c0col, c0col+64) for batch ab ----
    {
      float* h1s = red; float* gp = red + 512;
      h1s[tid] = h1_rd[ab*512 + tid];
      __syncthreads();
      int c = lane, ksx = wv;
      float accp = 0.f;
      const u16* wpd = a.WdecBF + (size_t)(ksx*64)*512 + c0col + c;
#pragma unroll 8
      for (int i=0;i<64;++i) accp = fmaf(h1s[ksx*64+i], bf2f(wpd[(size_t)i*512]), accp);
      gp[ksx*64+c] = accp;
      __syncthreads();
      if (tid < 64){
        float s = a.bdec[c0col+tid];
#pragma unroll
        for (int k=0;k<8;++k) s += gp[k*64+tid];
        AT_STORE(&at_wr[ab*512 + c0col + tid], s);
      }
    }
    // group arrive (att2 group: 8 blocks sharing batch ab)
    __syncthreads();
    if (tid == 0) AT_STORE(&a.sync[GRP_B + (grp*8 + as)*32], t+1);

    // ---- overlap A: P5a = Whh1 @ h1(t-1) -> pa1 ----
    {
      float a1[8];
#pragma unroll
      for (int r=0;r<8;++r) a1[r] = 0.f;
      const float* sp = h1_rd + bb*512 + ksg*32;
      f32x4 x[8];
#pragma unroll
      for (int q=0;q<8;++q) x[q] = *(const f32x4*)(sp + q*4);
      const float* wb = w1s + 512 + ksg*4;   // ch1 = Whh1
#pragma unroll
      for (int q=0;q<8;++q){
        f32x4 xq = x[q];
#pragma unroll
        for (int r=0;r<8;++r){
          f32x4 w4 = *(const f32x4*)(wb + r*1024 + q*64);
          a1[r] = fmaf(xq.x,w4.x, fmaf(xq.y,w4.y, fmaf(xq.z,w4.z, fmaf(xq.w,w4.w, a1[r]))));
        }
      }
#pragma unroll
      for (int r=0;r<8;++r){
        float v = a1[r];
        v += __shfl_xor(v,1); v += __shfl_xor(v,2); v += __shfl_xor(v,4); v += __shfl_xor(v,8);
        if (ksg == 0) pa1[r*33+bb] = v;
      }
    }
    // group wait
    if (tid < 8){
      while (AT_LOAD(&a.sync[GRP_B + (grp*8 + tid)*32]) < t+1) __builtin_amdgcn_s_sleep(1);
    }
    __syncthreads();
    asm volatile("" ::: "memory");

    // ---- P23: logits + softmax + ctx col-slice ----
    {
      float* att2s = red; float* gp3 = red + 512; float* alph = red + 1024;
      att2s[tid] = at_rd[ab*512 + tid];
      __syncthreads();
      float a2[8], wf[8];
#pragma unroll
      for (int j=0;j<8;++j){ a2[j] = att2s[lane*8+j]; wf[j] = a.Wfull[lane*8+j]; }
      float bf0 = a.bfull[0];
      int np = (wv < 4) ? 25 : 24;
      for (int i=0;i<np;++i){
        int p = wv + i*8;
        const u16* ep = a.encattBF + ((size_t)(ab*P_ + p))*512 + lane*8;
        short8 ev = *(const short8*)ep;
        float s = 0.f;
#pragma unroll
        for (int j=0;j<8;++j)
          s += fmaxf(bf2f((u16)ev[j]) + a2[j], 0.f) * wf[j];
#pragma unroll
        for (int o=32;o>=1;o>>=1) s += __shfl_xor(s, o);
        if (lane == 0) alph[p] = __expf(s + bf0);
      }
      __syncthreads();
      if (wv == 0){
        float v = 0.f;
#pragma unroll
        for (int i=0;i<4;++i){ int p = lane + 64*i; if (p < P_) v += alph[p]; }
#pragma unroll
        for (int o=32;o>=1;o>>=1) v += __shfl_xor(v, o);
        if (lane == 0) SinvS = 1.0f / v;
      }
      int c = lane, pk = wv;
      float accp = 0.f;
      for (int i=0;i<25;++i){
        int p = pk + 8*i;
        if (p < P_) accp = fmaf(alph[p], a.enc[((size_t)(ab*P_ + p))*512 + c0col + c], accp);
      }
      gp3[pk*64+c] = accp;
      __syncthreads();
      if (tid < 64){
        float s = 0.f;
#pragma unroll
        for (int k=0;k<8;++k) s += gp3[k*64+tid];
        AT_STORE(&cx_wr[ab*512 + c0col + tid], s * SinvS);
      }
    }
    g_arrive(a.sync, geng+1);

    // ---- overlap B: Whh0 @ h0(t-1) -> pa0 += ----
    {
      float a0[8];
#pragma unroll
      for (int r=0;r<8;++r) a0[r] = 0.f;
      const float* hp_ = h0_rd + bb*512 + ksg*32;
      f32x4 x[8];
#pragma unroll
      for (int q=0;q<8;++q) x[q] = *(const f32x4*)(hp_ + q*4);
      const float* wb = w0s + 1024 + ksg*4;   // ch2 = Whh0
#pragma unroll
      for (int q=0;q<8;++q){
        f32x4 xq = x[q];
#pragma unroll
        for (int r=0;r<8;++r){
          f32x4 w4 = *(const f32x4*)(wb + r*1536 + q*64);
          a0[r] = fmaf(xq.x,w4.x, fmaf(xq.y,w4.y, fmaf(xq.z,w4.z, fmaf(xq.w,w4.w, a0[r]))));
        }
      }
#pragma unroll
      for (int r=0;r<8;++r){
        float v = a0[r];
        v += __shfl_xor(v,1); v += __shfl_xor(v,2); v += __shfl_xor(v,4); v += __shfl_xor(v,8);
        if (ksg == 0) pa0[r*33+bb] += v;
      }
    }
    g_wait(a.sync, geng+1);

    // ---- P4b: ctx channel + pa0 + finalize -> h0(t) ----
    {
      float ac[8];
#pragma unroll
      for (int r=0;r<8;++r) ac[r] = 0.f;
      const float* cs = cx_rd + bb*512 + ksg*32;
      f32x4 x[8];
#pragma unroll
      for (int q=0;q<8;++q) x[q] = *(const f32x4*)(cs + q*4);
      const float* wb = w0s + 512 + ksg*4;   // ch1 = ctx
#pragma unroll
      for (int q=0;q<8;++q){
        f32x4 xq = x[q];
#pragma unroll
        for (int r=0;r<8;++r){
          f32x4 w4 = *(const f32x4*)(wb + r*1536 + q*64);
          ac[r] = fmaf(xq.x,w4.x, fmaf(xq.y,w4.y, fmaf(xq.z,w4.z, fmaf(xq.w,w4.w, ac[r]))));
        }
      }
#pragma unroll
      for (int r=0;r<8;++r){
        float v = ac[r];
        v += __shfl_xor(v,1); v += __shfl_xor(v,2); v += __shfl_xor(v,4); v += __shfl_xor(v,8);
        ac[r] = v;
      }
      if (ksg == 0){
#pragma unroll
        for (int ci=0;ci<2;++ci){
          int cell = bid*2 + ci;
          float gi = ac[0+ci] + pa0[(0+ci)*33+bb] + a.bih0[cell]      + a.bhh0[cell];
          float gf = ac[2+ci] + pa0[(2+ci)*33+bb] + a.bih0[512+cell]  + a.bhh0[512+cell];
          float gg = ac[4+ci] + pa0[(4+ci)*33+bb] + a.bih0[1024+cell] + a.bhh0[1024+cell];
          float go = ac[6+ci] + pa0[(6+ci)*33+bb] + a.bih0[1536+cell] + a.bhh0[1536+cell];
          float cp = c0s[ci*32+bb];
          float cn = sigf(gf)*cp + sigf(gi)*tanhfast(gg);
          float hn = sigf(go)*tanhfast(cn);
          c0s[ci*32+bb] = cn;
          AT_STORE(&h0_wr[bb*512 + cell], hn);
        }
      }
    }
    g_arrive(a.sync, geng+2);
    g_wait(a.sync, geng+2);

    // ---- P5b: Wih1 @ h0(t) + pa1 + finalize -> h1(t), h1_all ----
    {
      float ac[8];
#pragma unroll
      for (int r=0;r<8;++r) ac[r] = 0.f;
      const float* sp = h0_wr + bb*512 + ksg*32;
      f32x4 x[8];
#pragma unroll
      for (int q=0;q<8;++q) x[q] = *(const f32x4*)(sp + q*4);
      const float* wb = w1s + ksg*4;   // ch0 = Wih1
#pragma unroll
      for (int q=0;q<8;++q){
        f32x4 xq = x[q];
#pragma unroll
        for (int r=0;r<8;++r){
          f32x4 w4 = *(const f32x4*)(wb + r*1024 + q*64);
          ac[r] = fmaf(xq.x,w4.x, fmaf(xq.y,w4.y, fmaf(xq.z,w4.z, fmaf(xq.w,w4.w, ac[r]))));
        }
      }
#pragma unroll
      for (int r=0;r<8;++r){
        float v = ac[r];
        v += __shfl_xor(v,1); v += __shfl_xor(v,2); v += __shfl_xor(v,4); v += __shfl_xor(v,8);
        ac[r] = v;
      }
      if (ksg == 0){
#pragma unroll
        for (int ci=0;ci<2;++ci){
          int cell = bid*2 + ci;
          float gi = ac[0+ci] + pa1[(0+ci)*33+bb] + a.bih1[cell]      + a.bhh1[cell];
          float gf = ac[2+ci] + pa1[(2+ci)*33+bb] + a.bih1[512+cell]  + a.bhh1[512+cell];
          float gg = ac[4+ci] + pa1[(4+ci)*33+bb] + a.bih1[1024+cell] + a.bhh1[1024+cell];
          float go = ac[6+ci] + pa1[(6+ci)*33+bb] + a.bih1[1536+cell] + a.bhh1[1536+cell];
          float cp = c1s[ci*32+bb];
          float cn = sigf(gf)*cp + sigf(gi)*tanhfast(gg);
          float hn = sigf(go)*tanhfast(cn);
          c1s[ci*32+bb] = cn;
          AT_STORE(&h1_wr[bb*512 + cell], hn);
          a.h1_all[((size_t)(bb*T_ + t))*512 + cell] = f2bf(hn);
        }
      }
    }
    g_arrive(a.sync, geng+3);

    // ---- overlap C: emb channel for step t+1 -> pa0 (overwrite) ----
    if (t+1 < T_){
      float a0[8];
#pragma unroll
      for (int r=0;r<8;++r) a0[r] = 0.f;
      int cap = a.caps[bb*T_ + t+1];
      const float* ep_ = a.embW + (size_t)cap*512 + ksg*32;
      f32x4 x[8];
#pragma unroll
      for (int q=0;q<8;++q) x[q] = *(const f32x4*)(ep_ + q*4);
      const float* wb = w0s + ksg*4;
#pragma unroll
      for (int q=0;q<8;++q){
        f32x4 xq = x[q];
#pragma unroll
        for (int r=0;r<8;++r){
          f32x4 w4 = *(const f32x4*)(wb + r*1536 + q*64);
          a0[r] = fmaf(xq.x,w4.x, fmaf(xq.y,w4.y, fmaf(xq.z,w4.z, fmaf(xq.w,w4.w, a0[r]))));
        }
      }
#pragma unroll
      for (int r=0;r<8;++r){
        float v = a0[r];
        v += __shfl_xor(v,1); v += __shfl_xor(v,2); v += __shfl_xor(v,4); v += __shfl_xor(v,8);
        if (ksg == 0) pa0[r*33+bb] = v;
      }
    }
    g_wait(a.sync, geng+3);
  }
}

// ---------- host ----------

extern "C" void kernel_launch(void* const* d_in, const int* in_sizes, int n_in,
                              void* d_out, int out_size, void* d_ws, size_t ws_size,
                              hipStream_t stream){
  const float* enc   = (const float*)d_in[0];
  const int*   caps  = (const int*)d_in[1];
  const float* embW  = (const float*)d_in[2];
  const float* fc_b  = (const float*)d_in[3];
  const float* Wenc  = (const float*)d_in[4];
  const float* benc  = (const float*)d_in[5];
  const float* Wdec  = (const float*)d_in[6];
  const float* bdec  = (const float*)d_in[7];
  const float* Wfull = (const float*)d_in[8];
  const float* bfull = (const float*)d_in[9];
  const float* Wih0  = (const float*)d_in[10];
  const float* Whh0  = (const float*)d_in[11];
  const float* bih0  = (const float*)d_in[12];
  const float* bhh0  = (const float*)d_in[13];
  const float* Wih1  = (const float*)d_in[14];
  const float* Whh1  = (const float*)d_in[15];
  const float* bih1  = (const float*)d_in[16];
  const float* bhh1  = (const float*)d_in[17];
  const float* Winh  = (const float*)d_in[18];
  const float* binh  = (const float*)d_in[19];
  const float* Winc  = (const float*)d_in[20];
  const float* binc  = (const float*)d_in[21];
  float* out = (float*)d_out;

  char* wsp = (char*)d_ws;
  size_t off = 0;
  auto alloc = [&](size_t bytes)->char*{
    char* p = wsp + off;
    off += (bytes + 255) & ~(size_t)255;
    return p;
  };
  u16*   A_enc    = (u16*)  alloc((size_t)6272*512*2);
  u16*   emb_bf   = (u16*)  alloc((size_t)V_*512*2);
  u16*   WencT    = (u16*)  alloc((size_t)512*512*2);
  u16*   WdecBF   = (u16*)  alloc((size_t)512*512*2);
  float* encatt   = (float*)alloc((size_t)6272*512*4);
  u16*   encattBF = (u16*)  alloc((size_t)6272*512*2);
  float* meanb    = (float*)alloc((size_t)32*512*4);
  float* W0f      = (float*)alloc((size_t)2048*1536*4);
  float* W1f      = (float*)alloc((size_t)2048*1024*4);
  float* h0g      = (float*)alloc((size_t)65*SLABF*4);
  float* h1g      = (float*)alloc((size_t)65*SLABF*4);
  float* att2g    = (float*)alloc((size_t)65*SLABF*4);
  float* ctxg     = (float*)alloc((size_t)65*SLABF*4);
  float* c0init   = (float*)alloc(32*512*4);
  float* c1init   = (float*)alloc(32*512*4);
  u16*   h1_all   = (u16*)  alloc((size_t)2048*512*2);
  int*   syncA    = (int*)  alloc(16640*4);
  if (off > ws_size) return;

  // setup
  hipMemsetAsync(syncA, 0, 16640*4, stream);
  k_cvt_bf16<<<1568, 256, 0, stream>>>(enc, A_enc, 401408);
  k_cvt_bf16<<<8000, 256, 0, stream>>>(embW, emb_bf, 2048000);
  k_cvt_bf16<<<128, 256, 0, stream>>>(Wdec, WdecBF, 32768);
  k_wencT   <<<128, 256, 0, stream>>>(Wenc, WencT);
  k_mean    <<<32, 256, 0, stream>>>(enc, meanb);
  k_init_state<<<256, 256, 0, stream>>>(meanb, Winh, binh, Winc, binc,
                                        h0g, h1g, c0init, c1init);   // slot 0 = init
  k_fuse_w<<<4096, 256, 0, stream>>>(Wih0, Whh0, Wih1, Whh1, W0f, W1f);
  k_gemm_bf16<<<dim3(49, 4), 256, 0, stream>>>(A_enc, WencT, benc, encatt, 512);
  k_cvt_bf16<<<1568, 256, 0, stream>>>(encatt, encattBF, 401408);

  // persistent recurrence (cooperative: guarantees 256-block co-residency)
  RA ra;
  ra.enc = enc; ra.caps = caps; ra.embW = embW;
  ra.WdecBF = WdecBF; ra.bdec = bdec; ra.Wfull = Wfull; ra.bfull = bfull;
  ra.encattBF = encattBF; ra.W0f = W0f; ra.W1f = W1f;
  ra.bih0 = bih0; ra.bhh0 = bhh0; ra.bih1 = bih1; ra.bhh1 = bhh1;
  ra.h0g = h0g; ra.h1g = h1g; ra.att2g = att2g; ra.ctxg = ctxg;
  ra.c0init = c0init; ra.c1init = c1init;
  ra.h1_all = h1_all; ra.sync = syncA;
  void* kp[] = { &ra };
  hipLaunchCooperativeKernel((const void*)k_recur, dim3(256), dim3(512), kp, 0, stream);

  // deferred tied-weight projection: out[2048][32000] = h1_all @ emb_W^T + fc_b
  k_gemm_bf16<<<dim3(16, 250), 256, 0, stream>>>(h1_all, emb_bf, fc_b, out, V_);
}

// Round 14
// 2464.688 us; speedup vs baseline: 1.7822x; 1.7822x over previous
//
#include <hip/hip_runtime.h>

typedef unsigned short u16;
typedef __attribute__((ext_vector_type(4))) float f32x4;
typedef __attribute__((ext_vector_type(2))) float f32x2;
typedef __attribute__((ext_vector_type(8))) short short8;

#define B_ 32
#define P_ 196
#define T_ 64
#define V_ 32000
#define SLABF 17408   // 68 KB slab stride in floats

// Cross-block exchange (proven r4-r13): producers = relaxed agent-scope atomic
// stores (write-through to MALL); consumers = plain cached loads on t-indexed
// slabs (fresh addresses per step -> no stale line; miss fills L2 -> XCD dedup).
#define AT_LOAD(p)     __hip_atomic_load((p), __ATOMIC_RELAXED, __HIP_MEMORY_SCOPE_AGENT)
#define AT_STORE(p,v)  __hip_atomic_store((p), (v), __ATOMIC_RELAXED, __HIP_MEMORY_SCOPE_AGENT)

__device__ __forceinline__ u16 f2bf(float x){
  unsigned int u = __float_as_uint(x);
  u += 0x7FFFu + ((u >> 16) & 1u);
  return (u16)(u >> 16);
}
__device__ __forceinline__ float bf2f(u16 x){
  return __uint_as_float(((unsigned int)x) << 16);
}
__device__ __forceinline__ float sigf(float x){ return 1.0f/(1.0f + __expf(-x)); }
__device__ __forceinline__ float tanhfast(float x){
  float e = __expf(-2.0f*fabsf(x));
  float t = (1.0f - e)/(1.0f + e);
  return x >= 0.0f ? t : -t;
}

// ---------- setup kernels ----------

__global__ __launch_bounds__(256) void k_cvt_bf16(const float* __restrict__ s,
                                                  u16* __restrict__ d, int n8){
  int i = blockIdx.x*256 + threadIdx.x;
  if (i >= n8) return;
  const f32x4* sp = (const f32x4*)(s + (size_t)i*8);
  f32x4 a = sp[0], b = sp[1];
  short8 v;
#pragma unroll
  for (int j=0;j<4;++j){ v[j] = (short)f2bf(a[j]); v[4+j] = (short)f2bf(b[j]); }
  *(short8*)(d + (size_t)i*8) = v;
}

__global__ __launch_bounds__(256) void k_wencT(const float* __restrict__ W, u16* __restrict__ WT){
  int tid = threadIdx.x;
  int kc = tid & 63, a = blockIdx.x*4 + (tid >> 6);
  short8 v;
#pragma unroll
  for (int j=0;j<8;++j) v[j] = (short)f2bf(W[(kc*8+j)*512 + a]);
  *(short8*)(WT + a*512 + kc*8) = v;
}

__global__ __launch_bounds__(256) void k_mean(const float* __restrict__ enc, float* __restrict__ mean){
  int b = blockIdx.x, tid = threadIdx.x;
  f32x2 acc; acc.x = 0.f; acc.y = 0.f;
  for (int p=0;p<P_;++p){
    f32x2 v = *(const f32x2*)(enc + ((size_t)(b*P_+p))*512 + tid*2);
    acc.x += v.x; acc.y += v.y;
  }
  acc.x *= (1.0f/196.0f); acc.y *= (1.0f/196.0f);
  *(f32x2*)(mean + b*512 + tid*2) = acc;
}

__global__ __launch_bounds__(256) void k_init_state(const float* __restrict__ mean,
    const float* __restrict__ Wh, const float* __restrict__ bh,
    const float* __restrict__ Wc, const float* __restrict__ bc,
    float* __restrict__ h0, float* __restrict__ h1,
    float* __restrict__ c0, float* __restrict__ c1){
  int bid = blockIdx.x;
  int which = bid >> 7, r = (bid >> 2) & 31, jg = bid & 3;
  const float* W = which ? Wc : Wh;
  const float* bb = which ? bc : bh;
  __shared__ float m[512];
  for (int i=threadIdx.x; i<512; i+=256) m[i] = mean[r*512 + i];
  __syncthreads();
  int j = jg*256 + threadIdx.x;
  float acc = bb[j];
  for (int e=0;e<512;++e) acc += m[e]*W[e*1024 + j];
  int l = r >> 4;
  int bb2 = ((r & 15) << 1) | (j >> 9);
  int hh = j & 511;
  float* dst = which ? (l ? c1 : c0) : (l ? h1 : h0);
  dst[bb2*512 + hh] = acc;
}

// fused LSTM weights: W0f[2048][1536] = [Wih0 | Whh0], W1f[2048][1024] = [Wih1 | Whh1]
__global__ __launch_bounds__(256) void k_fuse_w(const float* __restrict__ Wih0,
    const float* __restrict__ Whh0, const float* __restrict__ Wih1,
    const float* __restrict__ Whh1, float* __restrict__ W0f, float* __restrict__ W1f){
  int r = blockIdx.x, tid = threadIdx.x;
  if (r < 2048){
    for (int k=tid; k<1536; k+=256)
      W0f[(size_t)r*1536+k] = (k<1024) ? Wih0[(size_t)r*1024+k] : Whh0[(size_t)r*512 + (k-1024)];
  } else {
    int r1 = r - 2048;
    for (int k=tid; k<1024; k+=256)
      W1f[(size_t)r1*1024+k] = (k<512) ? Wih1[(size_t)r1*512+k] : Whh1[(size_t)r1*512 + (k-512)];
  }
}

// ---------- bf16 GEMM (LDS pad 40 u16): C[M][N] = A[M][512]*Bm[N][512]^T + bias ----------
#define LDAP 40
__global__ __launch_bounds__(256) void k_gemm_bf16(
    const u16* __restrict__ A, const u16* __restrict__ Bm,
    const float* __restrict__ bias, float* __restrict__ C, int N){
  __shared__ __align__(16) u16 As[128*LDAP];
  __shared__ __align__(16) u16 Bs[128*LDAP];
  int tid = threadIdx.x, l = tid & 63, w = tid >> 6;
  int m0 = blockIdx.x * 128, n0 = blockIdx.y * 128;
  int wm = w >> 1, wn = w & 1;
  f32x4 acc[4][4];
#pragma unroll
  for (int a=0;a<4;++a)
#pragma unroll
    for (int b=0;b<4;++b) acc[a][b] = (f32x4)0.0f;
  int srow = tid >> 2, schunk = tid & 3;
  const u16* gA = A + (size_t)(m0 + srow)*512 + schunk*8;
  const u16* gB = Bm + (size_t)(n0 + srow)*512 + schunk*8;
  int lr = l & 15, lk = (l >> 4) * 8;
  for (int k0 = 0; k0 < 512; k0 += 32){
    short8 va0 = *(const short8*)(gA + k0);
    short8 va1 = *(const short8*)(gA + (size_t)64*512 + k0);
    short8 vb0 = *(const short8*)(gB + k0);
    short8 vb1 = *(const short8*)(gB + (size_t)64*512 + k0);
    __syncthreads();
    *(short8*)(As + srow*LDAP + schunk*8) = va0;
    *(short8*)(As + (64+srow)*LDAP + schunk*8) = va1;
    *(short8*)(Bs + srow*LDAP + schunk*8) = vb0;
    *(short8*)(Bs + (64+srow)*LDAP + schunk*8) = vb1;
    __syncthreads();
    short8 af[4], bfv[4];
#pragma unroll
    for (int mt=0; mt<4; ++mt) af[mt]  = *(const short8*)(As + (wm*64 + mt*16 + lr)*LDAP + lk);
#pragma unroll
    for (int nt=0; nt<4; ++nt) bfv[nt] = *(const short8*)(Bs + (wn*64 + nt*16 + lr)*LDAP + lk);
#pragma unroll
    for (int mt=0; mt<4; ++mt)
#pragma unroll
      for (int nt=0; nt<4; ++nt)
        acc[mt][nt] = __builtin_amdgcn_mfma_f32_16x16x32_bf16(af[mt], bfv[nt], acc[mt][nt], 0, 0, 0);
  }
#pragma unroll
  for (int mt=0; mt<4; ++mt){
    int row = m0 + wm*64 + mt*16 + ((l >> 4) << 2);
#pragma unroll
    for (int nt=0; nt<4; ++nt){
      int col = n0 + wn*64 + nt*16 + (l & 15);
      float bv = bias[col];
#pragma unroll
      for (int j=0;j<4;++j)
        C[(size_t)(row + j)*N + col] = acc[mt][nt][j] + bv;
    }
  }
}

// ---------- persistent recurrence kernel ----------

struct RA {
  const float* enc; const int* caps; const float* embW;
  const u16* WdecBF; const float* bdec; const float* Wfull; const float* bfull;
  const u16* encattBF; const float* W0f; const float* W1f;
  const float* bih0; const float* bhh0; const float* bih1; const float* bhh1;
  float* h0g; float* h1g; float* att2g; float* ctxg;    // t-indexed slabs
  const float* c0init; const float* c1init;
  u16* h1_all; int* sync;
};

// Single-hop all-poll-all grid barrier. sync[]: 256 arrival slots at 128B
// stride. Every block stores its slot; its 256 threads then poll the 256
// slots IN PARALLEL (one each, own slot skipped). Detection after the last
// arrival = one poll round-trip -- no block0 gather hop, no go-line hop.
__device__ __forceinline__ void gbar(int* sync, int gen){
  __syncthreads();   // drain this block's data stores before the flag store
  int tid = threadIdx.x;
  if (tid == 0) AT_STORE(&sync[blockIdx.x*32], gen);
  if (tid < 256 && tid != blockIdx.x){
    while (AT_LOAD(&sync[tid*32]) < gen) __builtin_amdgcn_s_sleep(4);
  }
  __syncthreads();
  asm volatile("" ::: "memory");  // no load hoisting above the poll
}

// LSTM weights LDS-resident, swizzled (r8): float k = ks*32+q*4+e of (row,ch)
// stored at [row][ch*512 + q*64 + ks*4 + e]. A wave's ds_read_b128 then has
// 16 distinct addresses, 2 per bank-quad (2-way = free), 4-lane broadcast.
__global__ __launch_bounds__(512) void k_recur(RA a){
  int bid = blockIdx.x, tid = threadIdx.x;
  int lane = tid & 63, wv = tid >> 6;
  __shared__ __align__(16) float w0s[12288];  // 48 KB: 8 rows x 1536
  __shared__ __align__(16) float w1s[8192];   // 32 KB: 8 rows x 1024
  __shared__ float red[2048];                 // P1: h1s|gp ; P23: att2s|gp3|alph
  __shared__ float c0s[64], c1s[64];          // [ci*32 + b]
  __shared__ float SinvS;
  __shared__ int capl[32];

  int xcd = bid & 7;
  // attention role: 4 batches per XCD (encatt/enc L2-resident), 8 col-slices
  int ab = xcd*4 + ((bid >> 3) & 3);
  int as = bid >> 5, c0col = as*64;
  // LSTM role: block owns cells bid*2, bid*2+1 for ALL 32 batches
  int bb = tid >> 4, ksg = tid & 15;    // batch 0..31, k-slice (32 floats) 0..15

  // one-time: weight rows -> LDS swizzled. local row r = g*2+ci.
  for (int idx = tid; idx < 12288; idx += 512){
    int r = idx / 1536, rem = idx - r*1536;
    int ch = rem >> 9, rem2 = rem & 511;
    int q = rem2 >> 6, rem3 = rem2 & 63;
    int ks = rem3 >> 2, e = rem3 & 3;
    int grow = (r >> 1)*512 + bid*2 + (r & 1);
    w0s[idx] = a.W0f[(size_t)grow*1536 + ch*512 + ks*32 + q*4 + e];
  }
  for (int idx = tid; idx < 8192; idx += 512){
    int r = idx >> 10, rem = idx & 1023;
    int ch = rem >> 9, rem2 = rem & 511;
    int q = rem2 >> 6, rem3 = rem2 & 63;
    int ks = rem3 >> 2, e = rem3 & 3;
    int grow = (r >> 1)*512 + bid*2 + (r & 1);
    w1s[idx] = a.W1f[(size_t)grow*1024 + ch*512 + ks*32 + q*4 + e];
  }
  if (tid < 64){
    int ci = tid >> 5, b = tid & 31, cell = bid*2 + ci;
    c0s[ci*32+b] = a.c0init[b*512 + cell];
    c1s[ci*32+b] = a.c1init[b*512 + cell];
  }
  __syncthreads();

  for (int t = 0; t < T_; ++t){
    const float* h1_rd = a.h1g + (size_t)t*SLABF;        // h1(t-1); slot0 = init
    const float* h0_rd = a.h0g + (size_t)t*SLABF;
    float*       h0_wr = a.h0g + (size_t)(t+1)*SLABF;
    float*       h1_wr = a.h1g + (size_t)(t+1)*SLABF;
    float*       at_wr = a.att2g + (size_t)t*SLABF;
    const float* at_rd = at_wr;
    float*       cx_wr = a.ctxg + (size_t)t*SLABF;
    const float* cx_rd = cx_wr;
    int genb = t*4;

    // ---- P1: att2 cols [c0col, c0col+64) for batch ab ----
    {
      float* h1s = red; float* gp = red + 512;
      h1s[tid] = h1_rd[ab*512 + tid];                 // plain cached (fresh slab)
      __syncthreads();
      int c = lane, ksx = wv;
      float accp = 0.f;
      const u16* wpd = a.WdecBF + (size_t)(ksx*64)*512 + c0col + c;
#pragma unroll 8
      for (int i=0;i<64;++i) accp = fmaf(h1s[ksx*64+i], bf2f(wpd[(size_t)i*512]), accp);
      gp[ksx*64+c] = accp;
      __syncthreads();
      if (tid < 64){
        float s = a.bdec[c0col+tid];
#pragma unroll
        for (int k=0;k<8;++k) s += gp[k*64+tid];
        AT_STORE(&at_wr[ab*512 + c0col + tid], s);
      }
    }
    gbar(a.sync, genb+1);

    // ---- P23: logits + softmax (redundant per block) + ctx col-slice ----
    {
      float* att2s = red; float* gp3 = red + 512; float* alph = red + 1024;
      att2s[tid] = at_rd[ab*512 + tid];               // plain cached
      __syncthreads();
      float a2[8], wf[8];
#pragma unroll
      for (int j=0;j<8;++j){ a2[j] = att2s[lane*8+j]; wf[j] = a.Wfull[lane*8+j]; }
      float bf0 = a.bfull[0];
      int np = (wv < 4) ? 25 : 24;
      for (int i=0;i<np;++i){
        int p = wv + i*8;
        const u16* ep = a.encattBF + ((size_t)(ab*P_ + p))*512 + lane*8;
        short8 ev = *(const short8*)ep;
        float s = 0.f;
#pragma unroll
        for (int j=0;j<8;++j)
          s += fmaxf(bf2f((u16)ev[j]) + a2[j], 0.f) * wf[j];
#pragma unroll
        for (int o=32;o>=1;o>>=1) s += __shfl_xor(s, o);
        if (lane == 0) alph[p] = __expf(s + bf0);
      }
      __syncthreads();
      if (wv == 0){
        float v = 0.f;
#pragma unroll
        for (int i=0;i<4;++i){ int p = lane + 64*i; if (p < P_) v += alph[p]; }
#pragma unroll
        for (int o=32;o>=1;o>>=1) v += __shfl_xor(v, o);
        if (lane == 0) SinvS = 1.0f / v;
      }
      int c = lane, pk = wv;
      float accp = 0.f;
      for (int i=0;i<25;++i){
        int p = pk + 8*i;
        if (p < P_) accp = fmaf(alph[p], a.enc[((size_t)(ab*P_ + p))*512 + c0col + c], accp);
      }
      gp3[pk*64+c] = accp;
      __syncthreads();
      if (tid < 64){
        float s = 0.f;
#pragma unroll
        for (int k=0;k<8;++k) s += gp3[k*64+tid];
        AT_STORE(&cx_wr[ab*512 + c0col + tid], s * SinvS);
      }
    }
    gbar(a.sync, genb+2);

    // ---- P4: LSTM layer 0 — cells bid*2..+1, all 32 batches ----
    {
      if (tid < 32) capl[tid] = a.caps[tid*T_ + t];
      __syncthreads();
      float acc[8];
#pragma unroll
      for (int r=0;r<8;++r) acc[r] = 0.f;
#pragma unroll
      for (int ch=0; ch<3; ++ch){
        const float* src;
        if (ch == 0)      src = a.embW + (size_t)capl[bb]*512 + ksg*32;
        else if (ch == 1) src = cx_rd + bb*512 + ksg*32;
        else              src = h0_rd + bb*512 + ksg*32;
        f32x4 x[8];
#pragma unroll
        for (int q=0;q<8;++q) x[q] = *(const f32x4*)(src + q*4);
        const float* wb = w0s + ch*512 + ksg*4;
#pragma unroll
        for (int q=0;q<8;++q){
          f32x4 xq = x[q];
#pragma unroll
          for (int r=0;r<8;++r){
            f32x4 w4 = *(const f32x4*)(wb + r*1536 + q*64);
            acc[r] = fmaf(xq.x,w4.x, fmaf(xq.y,w4.y, fmaf(xq.z,w4.z, fmaf(xq.w,w4.w, acc[r]))));
          }
        }
      }
#pragma unroll
      for (int r=0;r<8;++r){
        float v = acc[r];
        v += __shfl_xor(v,1); v += __shfl_xor(v,2); v += __shfl_xor(v,4); v += __shfl_xor(v,8);
        acc[r] = v;
      }
      if (ksg == 0){   // one lane per batch: finalize both cells
#pragma unroll
        for (int ci=0;ci<2;++ci){
          int cell = bid*2 + ci;
          float gi = acc[0+ci] + a.bih0[cell]        + a.bhh0[cell];
          float gf = acc[2+ci] + a.bih0[512+cell]    + a.bhh0[512+cell];
          float gg = acc[4+ci] + a.bih0[1024+cell]   + a.bhh0[1024+cell];
          float go = acc[6+ci] + a.bih0[1536+cell]   + a.bhh0[1536+cell];
          float cp = c0s[ci*32+bb];
          float cn = sigf(gf)*cp + sigf(gi)*tanhfast(gg);
          float hn = sigf(go)*tanhfast(cn);
          c0s[ci*32+bb] = cn;
          AT_STORE(&h0_wr[bb*512 + cell], hn);
        }
      }
    }
    gbar(a.sync, genb+3);

    // ---- P5: LSTM layer 1 ----
    {
      float acc[8];
#pragma unroll
      for (int r=0;r<8;++r) acc[r] = 0.f;
#pragma unroll
      for (int ch=0; ch<2; ++ch){
        const float* src = (ch == 0) ? (h0_wr + bb*512 + ksg*32)
                                     : (h1_rd + bb*512 + ksg*32);
        f32x4 x[8];
#pragma unroll
        for (int q=0;q<8;++q) x[q] = *(const f32x4*)(src + q*4);
        const float* wb = w1s + ch*512 + ksg*4;
#pragma unroll
        for (int q=0;q<8;++q){
          f32x4 xq = x[q];
#pragma unroll
          for (int r=0;r<8;++r){
            f32x4 w4 = *(const f32x4*)(wb + r*1024 + q*64);
            acc[r] = fmaf(xq.x,w4.x, fmaf(xq.y,w4.y, fmaf(xq.z,w4.z, fmaf(xq.w,w4.w, acc[r]))));
          }
        }
      }
#pragma unroll
      for (int r=0;r<8;++r){
        float v = acc[r];
        v += __shfl_xor(v,1); v += __shfl_xor(v,2); v += __shfl_xor(v,4); v += __shfl_xor(v,8);
        acc[r] = v;
      }
      if (ksg == 0){
#pragma unroll
        for (int ci=0;ci<2;++ci){
          int cell = bid*2 + ci;
          float gi = acc[0+ci] + a.bih1[cell]        + a.bhh1[cell];
          float gf = acc[2+ci] + a.bih1[512+cell]    + a.bhh1[512+cell];
          float gg = acc[4+ci] + a.bih1[1024+cell]   + a.bhh1[1024+cell];
          float go = acc[6+ci] + a.bih1[1536+cell]   + a.bhh1[1536+cell];
          float cp = c1s[ci*32+bb];
          float cn = sigf(gf)*cp + sigf(gi)*tanhfast(gg);
          float hn = sigf(go)*tanhfast(cn);
          c1s[ci*32+bb] = cn;
          AT_STORE(&h1_wr[bb*512 + cell], hn);
          a.h1_all[((size_t)(bb*T_ + t))*512 + cell] = f2bf(hn);
        }
      }
    }
    gbar(a.sync, genb+4);
  }
}

// ---------- host ----------

extern "C" void kernel_launch(void* const* d_in, const int* in_sizes, int n_in,
                              void* d_out, int out_size, void* d_ws, size_t ws_size,
                              hipStream_t stream){
  const float* enc   = (const float*)d_in[0];
  const int*   caps  = (const int*)d_in[1];
  const float* embW  = (const float*)d_in[2];
  const float* fc_b  = (const float*)d_in[3];
  const float* Wenc  = (const float*)d_in[4];
  const float* benc  = (const float*)d_in[5];
  const float* Wdec  = (const float*)d_in[6];
  const float* bdec  = (const float*)d_in[7];
  const float* Wfull = (const float*)d_in[8];
  const float* bfull = (const float*)d_in[9];
  const float* Wih0  = (const float*)d_in[10];
  const float* Whh0  = (const float*)d_in[11];
  const float* bih0  = (const float*)d_in[12];
  const float* bhh0  = (const float*)d_in[13];
  const float* Wih1  = (const float*)d_in[14];
  const float* Whh1  = (const float*)d_in[15];
  const float* bih1  = (const float*)d_in[16];
  const float* bhh1  = (const float*)d_in[17];
  const float* Winh  = (const float*)d_in[18];
  const float* binh  = (const float*)d_in[19];
  const float* Winc  = (const float*)d_in[20];
  const float* binc  = (const float*)d_in[21];
  float* out = (float*)d_out;

  char* wsp = (char*)d_ws;
  size_t off = 0;
  auto alloc = [&](size_t bytes)->char*{
    char* p = wsp + off;
    off += (bytes + 255) & ~(size_t)255;
    return p;
  };
  u16*   A_enc    = (u16*)  alloc((size_t)6272*512*2);
  u16*   emb_bf   = (u16*)  alloc((size_t)V_*512*2);
  u16*   WencT    = (u16*)  alloc((size_t)512*512*2);
  u16*   WdecBF   = (u16*)  alloc((size_t)512*512*2);
  float* encatt   = (float*)alloc((size_t)6272*512*4);
  u16*   encattBF = (u16*)  alloc((size_t)6272*512*2);
  float* meanb    = (float*)alloc((size_t)32*512*4);
  float* W0f      = (float*)alloc((size_t)2048*1536*4);
  float* W1f      = (float*)alloc((size_t)2048*1024*4);
  float* h0g      = (float*)alloc((size_t)65*SLABF*4);
  float* h1g      = (float*)alloc((size_t)65*SLABF*4);
  float* att2g    = (float*)alloc((size_t)65*SLABF*4);
  float* ctxg     = (float*)alloc((size_t)65*SLABF*4);
  float* c0init   = (float*)alloc(32*512*4);
  float* c1init   = (float*)alloc(32*512*4);
  u16*   h1_all   = (u16*)  alloc((size_t)2048*512*2);
  int*   syncA    = (int*)  alloc(8192*4);
  if (off > ws_size) return;

  // setup
  hipMemsetAsync(syncA, 0, 8192*4, stream);
  k_cvt_bf16<<<1568, 256, 0, stream>>>(enc, A_enc, 401408);
  k_cvt_bf16<<<8000, 256, 0, stream>>>(embW, emb_bf, 2048000);
  k_cvt_bf16<<<128, 256, 0, stream>>>(Wdec, WdecBF, 32768);
  k_wencT   <<<128, 256, 0, stream>>>(Wenc, WencT);
  k_mean    <<<32, 256, 0, stream>>>(enc, meanb);
  k_init_state<<<256, 256, 0, stream>>>(meanb, Winh, binh, Winc, binc,
                                        h0g, h1g, c0init, c1init);   // slot 0 = init
  k_fuse_w<<<4096, 256, 0, stream>>>(Wih0, Whh0, Wih1, Whh1, W0f, W1f);
  k_gemm_bf16<<<dim3(49, 4), 256, 0, stream>>>(A_enc, WencT, benc, encatt, 512);
  k_cvt_bf16<<<1568, 256, 0, stream>>>(encatt, encattBF, 401408);

  // persistent recurrence (cooperative: guarantees 256-block co-residency)
  RA ra;
  ra.enc = enc; ra.caps = caps; ra.embW = embW;
  ra.WdecBF = WdecBF; ra.bdec = bdec; ra.Wfull = Wfull; ra.bfull = bfull;
  ra.encattBF = encattBF; ra.W0f = W0f; ra.W1f = W1f;
  ra.bih0 = bih0; ra.bhh0 = bhh0; ra.bih1 = bih1; ra.bhh1 = bhh1;
  ra.h0g = h0g; ra.h1g = h1g; ra.att2g = att2g; ra.ctxg = ctxg;
  ra.c0init = c0init; ra.c1init = c1init;
  ra.h1_all = h1_all; ra.sync = syncA;
  void* kp[] = { &ra };
  hipLaunchCooperativeKernel((const void*)k_recur, dim3(256), dim3(512), kp, 0, stream);

  // deferred tied-weight projection: out[2048][32000] = h1_all @ emb_W^T + fc_b
  k_gemm_bf16<<<dim3(16, 250), 256, 0, stream>>>(h1_all, emb_bf, fc_b, out, V_);
}